// Round 7
// baseline (144.358 us; speedup 1.0000x reference)
//
#include <hip/hip_runtime.h>
#include <hip/hip_bf16.h>
#include <math.h>

#define B 4
#define L 2048
#define D 256
#define H 8
#define HD 32
#define SCALE 0.17677669529663687f
#define LOG2E 1.4426950408889634f
#define QSCL (SCALE * LOG2E)

typedef __attribute__((ext_vector_type(8))) short short8;
typedef __attribute__((ext_vector_type(4))) short short4v;
typedef __attribute__((ext_vector_type(4))) float f32x4;

__device__ inline short f2bf(float x) {
  union { float f; unsigned u; } c; c.f = x;
  unsigned r = (c.u + 0x7FFFu + ((c.u >> 16) & 1u)) >> 16;
  return (short)r;
}

// NOTE (R5/R6 post-mortem): do NOT use v_permlane16/32_swap with duplicated
// inputs (a=b=x) as a reduce primitive — it failed on HW (absmax ~0.7).
// Cross-lane reductions here use __shfl_xor (exact permute, R4-proven).

// ---------------- prep: x f32 -> bf16 ---------------------------------------
__global__ __launch_bounds__(256) void prep_xb(const float* __restrict__ x,
                                               short* __restrict__ xb) {
  int i = (blockIdx.x * 256 + threadIdx.x) * 8;
  f32x4 a = *reinterpret_cast<const f32x4*>(x + i);
  f32x4 b = *reinterpret_cast<const f32x4*>(x + i + 4);
  short8 o;
#pragma unroll
  for (int j = 0; j < 4; ++j) { o[j] = f2bf(a[j]); o[4 + j] = f2bf(b[j]); }
  *reinterpret_cast<short8*>(xb + i) = o;
}

// ---------------- prep: W [256,N] f32 -> W^T [N,256] bf16 (LDS tiled) -------
__global__ __launch_bounds__(256) void prep_wt(const float* __restrict__ w,
                                               short* __restrict__ wt, int N) {
  __shared__ short tile[32][33];
  int k0 = blockIdx.x * 32;
  int n0 = blockIdx.y * 32;
  int tx = threadIdx.x & 31, ty = threadIdx.x >> 5;
#pragma unroll
  for (int i = 0; i < 32; i += 8)
    tile[ty + i][tx] = f2bf(w[(k0 + ty + i) * N + n0 + tx]);
  __syncthreads();
#pragma unroll
  for (int i = 0; i < 32; i += 8)
    wt[(n0 + ty + i) * 256 + k0 + tx] = tile[tx][ty + i];
}

// ---------------- Kernel 1: qkv = xb @ Wqkv, head-split outputs -------------
__global__ __launch_bounds__(64) void qkv_gemm(const short* __restrict__ xb,
                                               const short* __restrict__ wt,
                                               short* __restrict__ qb,
                                               short* __restrict__ kb,
                                               short* __restrict__ vt) {
  int bid = blockIdx.x;
  int mt = bid / 12, nt = bid % 12;
  int m0 = mt * 64, n0 = nt * 64;
  int l = threadIdx.x, ra = l & 15, g = l >> 4;

  f32x4 acc[4][4] = {};
  for (int k0 = 0; k0 < 256; k0 += 32) {
    int kk = k0 + g * 8;
    short8 bfr[4], afr[4];
#pragma unroll
    for (int nf = 0; nf < 4; ++nf)
      bfr[nf] = *reinterpret_cast<const short8*>(&wt[(n0 + nf * 16 + ra) * 256 + kk]);
#pragma unroll
    for (int mf = 0; mf < 4; ++mf)
      afr[mf] = *reinterpret_cast<const short8*>(&xb[(m0 + mf * 16 + ra) * 256 + kk]);
#pragma unroll
    for (int mf = 0; mf < 4; ++mf)
#pragma unroll
      for (int nf = 0; nf < 4; ++nf)
        acc[mf][nf] = __builtin_amdgcn_mfma_f32_16x16x32_bf16(afr[mf], bfr[nf], acc[mf][nf], 0, 0, 0);
  }

  int sec = n0 >> 8;   // 0=q 1=k 2=v (uniform per block)
  float scl = (sec == 0) ? QSCL : 1.0f;
#pragma unroll
  for (int nf = 0; nf < 4; ++nf) {
    int n = n0 + nf * 16 + ra;
    int c = n & 255;
    int h = c >> 5, d = c & 31;
#pragma unroll
    for (int mf = 0; mf < 4; ++mf) {
#pragma unroll
      for (int r = 0; r < 4; ++r) {
        int mm = m0 + mf * 16 + g * 4 + r;
        int b = mm >> 11, lpos = mm & 2047;
        short val = f2bf(acc[mf][nf][r] * scl);
        if (sec == 2) vt[((b * H + h) * HD + d) * L + lpos] = val;
        else {
          short* dst = (sec == 0) ? qb : kb;
          dst[((b * H + h) * L + lpos) * HD + d] = val;
        }
      }
    }
  }
}

// ---------------- Kernel 2: flash attention ---------------------------------
// Wave = 32 q-rows x 1 head (2 q-tiles). Block = 4 waves = 4 heads, same rows.
// Grid 512 blocks, 2 blocks/CU (2 waves/SIMD).
// XCD = bid&7 owns a contiguous 256-q-row slice -> its 2MB bias slice is
// L2-resident; K/V (8MB/XCD) streams from L3.
__global__ __launch_bounds__(256, 2) void attn_fwd(const short* __restrict__ qb,
                                                   const short* __restrict__ kb,
                                                   const short* __restrict__ vt,
                                                   const float* __restrict__ bias,
                                                   short* __restrict__ ob) {
  int wid = threadIdx.x >> 6;
  int l = threadIdx.x & 63;
  int ra = l & 15, g = l >> 4;
  bool oddg = (g & 1);
  int xcd = blockIdx.x & 7;
  int idx = blockIdx.x >> 3;     // 0..63
  int hg  = idx & 7;             // head-group
  int qg  = idx >> 3;            // 0..7
  int qt  = xcd * 8 + qg;        // 0..63 (32-row tiles)
  int bh  = hg * 4 + wid;
  int q0  = qt * 32;

  const short* kptr  = kb + bh * (L * HD) + ra * HD + g * 8;
  const short* vptr0 = vt + bh * (HD * L) + ra * L + g * 8;
  const short* vptr1 = vptr0 + 16 * L;
  const float* bbase = bias + (q0 + ra) * L + g * 4;

  short8 bq[2];
#pragma unroll
  for (int t4 = 0; t4 < 2; ++t4)
    bq[t4] = *reinterpret_cast<const short8*>(qb + (bh * L + q0 + t4 * 16 + ra) * HD + g * 8);

  f32x4 o0[2] = {}, o1[2] = {}, zf = {};
  float mrun[2], lsum[2];
#pragma unroll
  for (int t4 = 0; t4 < 2; ++t4) { mrun[t4] = -1e30f; lsum[t4] = 0.f; }

  short8 akA[4], akB[4], vaA[4], vaB[4];
  f32x4 bbX[2][4], bbY[2][4];

  auto LOADKV = [&](short8 (&ak)[4], short8 (&va)[4], int kv) {
#pragma unroll
    for (int c = 0; c < 4; ++c)
      ak[c] = *reinterpret_cast<const short8*>(kptr + (kv + 16 * c) * HD);
    va[0] = *reinterpret_cast<const short8*>(vptr0 + kv);
    va[1] = *reinterpret_cast<const short8*>(vptr0 + kv + 32);
    va[2] = *reinterpret_cast<const short8*>(vptr1 + kv);
    va[3] = *reinterpret_cast<const short8*>(vptr1 + kv + 32);
  };
  auto BLOAD = [&](f32x4 (&bb)[2][4], int kv) {
#pragma unroll
    for (int tt = 0; tt < 2; ++tt)
#pragma unroll
      for (int c = 0; c < 4; ++c)
        bb[tt][c] = *reinterpret_cast<const f32x4*>(bbase + tt * 16 * L + kv + 16 * c);
  };

  auto TILE = [&](int t4, short8 (&ak)[4], short8 (&va)[4], f32x4 (&bb)[4]) {
    f32x4 s0 = __builtin_amdgcn_mfma_f32_16x16x32_bf16(ak[0], bq[t4], zf, 0, 0, 0);
    f32x4 s1 = __builtin_amdgcn_mfma_f32_16x16x32_bf16(ak[1], bq[t4], zf, 0, 0, 0);
    f32x4 s2 = __builtin_amdgcn_mfma_f32_16x16x32_bf16(ak[2], bq[t4], zf, 0, 0, 0);
    f32x4 s3 = __builtin_amdgcn_mfma_f32_16x16x32_bf16(ak[3], bq[t4], zf, 0, 0, 0);

    float v[16];
#pragma unroll
    for (int r = 0; r < 4; ++r) {
      v[r]      = fmaf(bb[0][r], LOG2E, s0[r]);
      v[4 + r]  = fmaf(bb[1][r], LOG2E, s1[r]);
      v[8 + r]  = fmaf(bb[2][r], LOG2E, s2[r]);
      v[12 + r] = fmaf(bb[3][r], LOG2E, s3[r]);
    }
    // max3-shaped tree (clang fuses fmaxf pairs into v_max3_f32)
    float t0 = fmaxf(fmaxf(v[0], v[1]), v[2]);
    float t1 = fmaxf(fmaxf(v[3], v[4]), v[5]);
    float t2 = fmaxf(fmaxf(v[6], v[7]), v[8]);
    float t3 = fmaxf(fmaxf(v[9], v[10]), v[11]);
    float t4m = fmaxf(fmaxf(v[12], v[13]), v[14]);
    float pm = fmaxf(fmaxf(fmaxf(t0, t1), t2), fmaxf(fmaxf(t3, t4m), v[15]));
    // Exact-permute cross-lane reduce (R4-proven path).
    pm = fmaxf(pm, __shfl_xor(pm, 16));
    pm = fmaxf(pm, __shfl_xor(pm, 32));

    if (!__all(pm <= mrun[t4] + 8.0f)) {
      float mnew = fmaxf(mrun[t4], pm);
      float ad = mrun[t4] - mnew, al;
      asm("v_exp_f32 %0, %1" : "=v"(al) : "v"(ad));
      lsum[t4] *= al;
#pragma unroll
      for (int r = 0; r < 4; ++r) { o0[t4][r] *= al; o1[t4][r] *= al; }
      mrun[t4] = mnew;
    }
    float m = mrun[t4];
#pragma unroll
    for (int i = 0; i < 16; ++i) {
      float x = v[i] - m;
      asm("v_exp_f32 %0, %1" : "=v"(v[i]) : "v"(x));
    }
    float rs = 0.f;
#pragma unroll
    for (int i = 0; i < 16; ++i) rs += v[i];
    lsum[t4] += rs;            // per-lane partial; cross-lane reduce deferred

#pragma unroll
    for (int ch = 0; ch < 2; ++ch) {
      const float* pc = v + ch * 8;
      unsigned w01, w23, w45, w67;
      asm("v_cvt_pk_bf16_f32 %0, %1, %2" : "=v"(w01) : "v"(pc[0]), "v"(pc[1]));
      asm("v_cvt_pk_bf16_f32 %0, %1, %2" : "=v"(w23) : "v"(pc[2]), "v"(pc[3]));
      asm("v_cvt_pk_bf16_f32 %0, %1, %2" : "=v"(w45) : "v"(pc[4]), "v"(pc[5]));
      asm("v_cvt_pk_bf16_f32 %0, %1, %2" : "=v"(w67) : "v"(pc[6]), "v"(pc[7]));
      asm("v_permlane32_swap_b32 %0, %1" : "+v"(w01), "+v"(w45));
      asm("v_permlane32_swap_b32 %0, %1" : "+v"(w23), "+v"(w67));
      unsigned z1 = oddg ? w01 : w45;
      unsigned z2 = oddg ? w23 : w67;
      // ^16 exchange MUST be an exact permute -> shfl_xor (R4-proven).
      unsigned y1 = (unsigned)__shfl_xor((int)z1, 16);
      unsigned y2 = (unsigned)__shfl_xor((int)z2, 16);
      union { unsigned u[4]; short8 s; } pb;
      pb.u[0] = oddg ? y1 : w01;
      pb.u[1] = oddg ? y2 : w23;
      pb.u[2] = oddg ? w45 : y1;
      pb.u[3] = oddg ? w67 : y2;
      o0[t4] = __builtin_amdgcn_mfma_f32_16x16x32_bf16(va[ch], pb.s, o0[t4], 0, 0, 0);
      o1[t4] = __builtin_amdgcn_mfma_f32_16x16x32_bf16(va[2 + ch], pb.s, o1[t4], 0, 0, 0);
    }
  };

  LOADKV(akA, vaA, 0);
  BLOAD(bbX, 0);
  for (int t = 0; t < 32; t += 2) {
    LOADKV(akB, vaB, (t + 1) * 64);
    BLOAD(bbY, (t + 1) * 64);
    TILE(0, akA, vaA, bbX[0]);
    TILE(1, akA, vaA, bbX[1]);
    if (t + 2 < 32) { LOADKV(akA, vaA, (t + 2) * 64); BLOAD(bbX, (t + 2) * 64); }
    TILE(0, akB, vaB, bbY[0]);
    TILE(1, akB, vaB, bbY[1]);
  }

  int b = bh >> 3, h = bh & 7;
#pragma unroll
  for (int t4 = 0; t4 < 2; ++t4) {
    float ls = lsum[t4];
    ls += __shfl_xor(ls, 16);
    ls += __shfl_xor(ls, 32);
    float inv = 1.0f / ls;
    int row = (b * L + q0 + t4 * 16 + ra) * D + h * HD;
    short4v w0, w1;
#pragma unroll
    for (int r = 0; r < 4; ++r) { w0[r] = f2bf(o0[t4][r] * inv); w1[r] = f2bf(o1[t4][r] * inv); }
    *reinterpret_cast<short4v*>(ob + row + g * 4) = w0;
    *reinterpret_cast<short4v*>(ob + row + 16 + g * 4) = w1;
  }
}

// ---------------- Kernel 3: out = O @ Wout ----------------------------------
__global__ __launch_bounds__(64) void out_gemm(const short* __restrict__ obuf,
                                               const short* __restrict__ wt,
                                               float* __restrict__ out) {
  int bid = blockIdx.x;
  int nt = bid & 3, mt = bid >> 2;
  int m0 = mt * 64, n0 = nt * 64;
  int l = threadIdx.x, ra = l & 15, g = l >> 4;

  f32x4 acc[4][4] = {};
  for (int k0 = 0; k0 < 256; k0 += 32) {
    int kk = k0 + g * 8;
    short8 bfr[4], afr[4];
#pragma unroll
    for (int nf = 0; nf < 4; ++nf)
      bfr[nf] = *reinterpret_cast<const short8*>(&wt[(n0 + nf * 16 + ra) * 256 + kk]);
#pragma unroll
    for (int mf = 0; mf < 4; ++mf)
      afr[mf] = *reinterpret_cast<const short8*>(&obuf[(m0 + mf * 16 + ra) * 256 + kk]);
#pragma unroll
    for (int mf = 0; mf < 4; ++mf)
#pragma unroll
      for (int nf = 0; nf < 4; ++nf)
        acc[mf][nf] = __builtin_amdgcn_mfma_f32_16x16x32_bf16(afr[mf], bfr[nf], acc[mf][nf], 0, 0, 0);
  }
#pragma unroll
  for (int mf = 0; mf < 4; ++mf)
#pragma unroll
    for (int nf = 0; nf < 4; ++nf)
#pragma unroll
      for (int r = 0; r < 4; ++r)
        out[(m0 + mf * 16 + g * 4 + r) * 256 + n0 + nf * 16 + ra] = acc[mf][nf][r];
}

extern "C" void kernel_launch(void* const* d_in, const int* in_sizes, int n_in,
                              void* d_out, int out_size, void* d_ws, size_t ws_size,
                              hipStream_t stream) {
  const float* x    = (const float*)d_in[0];
  const float* bias = (const float*)d_in[1];
  const float* wqkv = (const float*)d_in[2];
  const float* wout = (const float*)d_in[3];
  float* out = (float*)d_out;

  short* xb     = (short*)d_ws;            // [8192,256]   2M shorts
  short* qb     = xb + B * L * D;          // [bh][L][HD]  2M
  short* kb     = qb + B * L * D;          // 2M
  short* vt     = kb + B * L * D;          // [bh][HD][L]  2M
  short* ob     = vt + B * L * D;          // [8192,256]   2M
  short* wqkvT  = ob + B * L * D;          // [768,256]
  short* woutT  = wqkvT + 768 * 256;       // [256,256]

  prep_xb<<<dim3(1024), dim3(256), 0, stream>>>(x, xb);
  prep_wt<<<dim3(8, 24), dim3(256), 0, stream>>>(wqkv, wqkvT, 768);
  prep_wt<<<dim3(8, 8), dim3(256), 0, stream>>>(wout, woutT, 256);
  qkv_gemm<<<dim3(1536), dim3(64), 0, stream>>>(xb, wqkvT, qb, kb, vt);
  attn_fwd<<<dim3(512), dim3(256), 0, stream>>>(qb, kb, vt, bias, ob);
  out_gemm<<<dim3(512), dim3(64), 0, stream>>>(ob, woutT, out);
}